// Round 8
// baseline (92.349 us; speedup 1.0000x reference)
//
#include <hip/hip_runtime.h>

// FHE BSGS: out[b,s] = sum_{t=0..15} x[b,(s+2^t)&0xFFFF] * diag[t,s], rolled by 32768.
// Roll by S/2 on the 2^16 ring == store to column s ^ 0x8000 (coalesced).
//
// v7b: v7 with the nontemporal builtin calls fixed -- they require native clang
// ext_vector_type pointers, not HIP_vector_type (compile error on gfx950).
//   - 8 row-groups of 8 rows; g = bid&7 == XCD (round-robin dispatch) -> per-XCD
//     x footprint 2 MB, L2-resident. Grid 2048 blocks.
//   - block = 256 cols x 8 rows; wave w takes rows 8g+2w..+1 (2 rows/thread).
//     diag tile (16 KB) staged in LDS once, nontemporal loads (don't evict x from
//     L2); single __syncthreads.
//   - nontemporal out stores (no write-allocate pollution).
//   - shuffle trick: shifts 4..128 synthesized on the DS pipe; 9 x-loads/row.
// Requests ~201 MB, x portion (151 MB) expected L2-served.

#define SLOTS 65536
#define MASK  65535
#define CTILE 256
#define RPT   2      // rows per thread

typedef float vfloat4 __attribute__((ext_vector_type(4)));  // native vec for nt builtins

__device__ __forceinline__ float4 shfl4(const float4 v, int lsel) {
    return make_float4(__shfl(v.x, lsel, 64), __shfl(v.y, lsel, 64),
                       __shfl(v.z, lsel, 64), __shfl(v.w, lsel, 64));
}

__global__ __launch_bounds__(256) void bsgs_kernel(
    const float* __restrict__ x,
    const float* __restrict__ diag,
    float* __restrict__ out)
{
    __shared__ float dlds[16 * CTILE];        // 16 KB diag tile
    const int bid  = blockIdx.x;              // 0..2047
    const int g    = bid & 7;                 // row group == XCD (bid % 8)
    const int c    = (bid >> 3) * CTILE;      // column tile base
    const int tid  = threadIdx.x;
    const int wave = tid >> 6;                // 0..3
    const int lane = tid & 63;
    const int j    = c + lane * 4;            // thread's column base (multiple of 4)
    const int row0 = g * 8 + wave * RPT;      // this thread's first batch row

    // Stage diag[0..16, c..c+256) into LDS, nontemporal, fully coalesced:
    // float4 index F = tid + 256k -> t = F>>6, q = F&63.
#pragma unroll
    for (int k = 0; k < 4; ++k) {
        const int F = tid + 256 * k;
        const int t = F >> 6, q = F & 63;
        const vfloat4 v = __builtin_nontemporal_load(
            (const vfloat4*)(diag + t * SLOTS + c + q * 4));
        *(vfloat4*)(dlds + t * CTILE + q * 4) = v;
    }
    __syncthreads();   // only barrier in the kernel

    // diag fragments for this thread's 4 columns (16 B stride -> 2-way aliasing, free)
    float4 dreg[16];
#pragma unroll
    for (int t = 0; t < 16; ++t)
        dreg[t] = *(const float4*)(dlds + t * CTILE + lane * 4);

    float4 acc[RPT];
#pragma unroll
    for (int r = 0; r < RPT; ++r) acc[r] = make_float4(0.f, 0.f, 0.f, 0.f);

#pragma unroll
    for (int r = 0; r < RPT; ++r) {
        const float* __restrict__ xr = x + (size_t)(row0 + r) * SLOTS;

        // 9 x-loads per row: vA, vE, and the 7 big shifts (all L2-resident).
        const float4 vA = *(const float4*)(xr + j);
        const float4 vE = *(const float4*)(xr + ((j + 256) & MASK));
        float4 vd[7];
#pragma unroll
        for (int t = 9; t < 16; ++t)
            vd[t - 9] = *(const float4*)(xr + ((j + (1 << t)) & MASK));

        // Windows at shifts 4,8,16,32,64,128 via cross-lane shuffles (DS pipe).
        float4 w[6];
#pragma unroll
        for (int i = 0; i < 6; ++i) {
            const int k  = 1 << i;            // lane offset = shift/4
            const int lp = lane + k;
            const int ls = lp & 63;
            const float4 a = shfl4(vA, ls);
            const float4 e = shfl4(vE, ls);
            const bool useA = lp < 64;
            w[i] = make_float4(useA ? a.x : e.x, useA ? a.y : e.y,
                               useA ? a.z : e.z, useA ? a.w : e.w);
        }

        // t=0 (shift 1) and t=1 (shift 2): component slides of vA / shift-4 window
        acc[r].x += vA.y   * dreg[0].x + vA.z   * dreg[1].x;
        acc[r].y += vA.z   * dreg[0].y + vA.w   * dreg[1].y;
        acc[r].z += vA.w   * dreg[0].z + w[0].x * dreg[1].z;
        acc[r].w += w[0].x * dreg[0].w + w[0].y * dreg[1].w;

        // t=2..7 (shifts 4..128): shuffle windows
#pragma unroll
        for (int t = 2; t <= 7; ++t) {
            const float4 v = w[t - 2];
            acc[r].x += v.x * dreg[t].x; acc[r].y += v.y * dreg[t].y;
            acc[r].z += v.z * dreg[t].z; acc[r].w += v.w * dreg[t].w;
        }
        // t=8 (shift 256): vE directly
        acc[r].x += vE.x * dreg[8].x; acc[r].y += vE.y * dreg[8].y;
        acc[r].z += vE.z * dreg[8].z; acc[r].w += vE.w * dreg[8].w;
        // t=9..15 (shifts 512..32768): direct loads
#pragma unroll
        for (int t = 9; t < 16; ++t) {
            const float4 v = vd[t - 9];
            acc[r].x += v.x * dreg[t].x; acc[r].y += v.y * dreg[t].y;
            acc[r].z += v.z * dreg[t].z; acc[r].w += v.w * dreg[t].w;
        }
    }

    // roll by 32768 == XOR top column bit; nontemporal coalesced stores
#pragma unroll
    for (int r = 0; r < RPT; ++r) {
        vfloat4 o;
        o.x = acc[r].x; o.y = acc[r].y; o.z = acc[r].z; o.w = acc[r].w;
        __builtin_nontemporal_store(o,
            (vfloat4*)(out + (size_t)(row0 + r) * SLOTS + (j ^ 32768)));
    }
}

extern "C" void kernel_launch(void* const* d_in, const int* in_sizes, int n_in,
                              void* d_out, int out_size, void* d_ws, size_t ws_size,
                              hipStream_t stream) {
    const float* x    = (const float*)d_in[0];   // (64, 65536) fp32
    const float* diag = (const float*)d_in[1];   // (16, 65536) fp32
    float* out        = (float*)d_out;           // (64, 65536) fp32
    // d_in[2] = stride (1), d_in[3] = reps (1) -- compile-time constants here.

    bsgs_kernel<<<dim3(2048), dim3(256), 0, stream>>>(x, diag, out);
}

// Round 9
// 85.136 us; speedup vs baseline: 1.0847x; 1.0847x over previous
//
#include <hip/hip_runtime.h>

// FHE BSGS: out[b,s] = sum_{t=0..15} x[b,(s+2^t)&0xFFFF] * diag[t,s], rolled by 32768.
// Roll by S/2 on the 2^16 ring == store to column s ^ 0x8000 (coalesced).
//
// v8 = v6 (empirical best, 84.3 us): NB=4 rows/thread, 1024 blocks, barrier-free,
// diag in registers, shifts 4..128 synthesized via wave shuffles on the DS pipe
// (9 x-loads/row instead of 15).
//
// Why this is the floor (calibrated v1..v7b): bench = ~60-65 us serialized harness
// replay (268+17 MB poison fills + 42 MB d_in restore at ~6.2 TB/s + dispatch gaps)
// + kernel window ~19-20 us. The kernel window itself is HBM-drain-bound: the
// harness's 268 MB 0xAA fill leaves ~100 MB dirty in the 256 MB LLC, which drains
// to HBM DURING our kernel (v3 profile: WRITE_SIZE=119 MB vs our 16.8 MB of
// stores). Request-byte reductions below ~240 MB are hidden under that drain --
// v2 (165 MB), v4 (336 MB), v6 (237 MB) all time identically. L2/XCD pinning
// refuted 3x (v5, v7, v7b).

#define SLOTS 65536
#define MASK  65535
#define NB    4

__device__ __forceinline__ float4 shfl4(const float4 v, int lsel) {
    return make_float4(__shfl(v.x, lsel, 64), __shfl(v.y, lsel, 64),
                       __shfl(v.z, lsel, 64), __shfl(v.w, lsel, 64));
}

__global__ __launch_bounds__(256) void bsgs_kernel(
    const float* __restrict__ x,
    const float* __restrict__ diag,
    float* __restrict__ out)
{
    const int bid  = blockIdx.x;          // 0..1023
    const int y    = bid & 15;            // batch group (bid%8 clusters pairs per XCD)
    const int xidx = bid >> 4;            // column tile 0..63
    const int j    = xidx * 1024 + threadIdx.x * 4;   // column base (multiple of 4)
    const int bg   = y * NB;
    const int lane = threadIdx.x & 63;

    // diag[t, j..j+3], t=0..15 -- reused across NB batch rows.
    float4 dreg[16];
#pragma unroll
    for (int t = 0; t < 16; ++t)
        dreg[t] = *(const float4*)(diag + t * SLOTS + j);

    float4 acc[NB];
#pragma unroll
    for (int b = 0; b < NB; ++b) acc[b] = make_float4(0.f, 0.f, 0.f, 0.f);

#pragma unroll
    for (int b = 0; b < NB; ++b) {
        const float* __restrict__ xr = x + (size_t)(bg + b) * SLOTS;

        // 9 loads per row: vA, vE, and the 7 big shifts.
        const float4 vA = *(const float4*)(xr + j);
        const float4 vE = *(const float4*)(xr + ((j + 256) & MASK));
        float4 vd[7];
#pragma unroll
        for (int t = 9; t < 16; ++t)
            vd[t - 9] = *(const float4*)(xr + ((j + (1 << t)) & MASK));

        // Windows at shifts 4,8,16,32,64,128 via cross-lane shuffles (DS pipe).
        float4 w[6];
#pragma unroll
        for (int i = 0; i < 6; ++i) {
            const int k  = 1 << i;             // lane offset = shift/4
            const int lp = lane + k;           // source lane (may spill into vE's window)
            const int ls = lp & 63;
            const float4 a = shfl4(vA, ls);
            const float4 e = shfl4(vE, ls);
            const bool useA = lp < 64;
            w[i] = make_float4(useA ? a.x : e.x, useA ? a.y : e.y,
                               useA ? a.z : e.z, useA ? a.w : e.w);
        }

        // t=0 (shift 1): (vA.y, vA.z, vA.w, w0.x);  t=1 (shift 2): (vA.z, vA.w, w0.x, w0.y)
        acc[b].x += vA.y   * dreg[0].x + vA.z   * dreg[1].x;
        acc[b].y += vA.z   * dreg[0].y + vA.w   * dreg[1].y;
        acc[b].z += vA.w   * dreg[0].z + w[0].x * dreg[1].z;
        acc[b].w += w[0].x * dreg[0].w + w[0].y * dreg[1].w;

        // t=2..7 (shifts 4..128): shuffle windows
#pragma unroll
        for (int t = 2; t <= 7; ++t) {
            const float4 v = w[t - 2];
            acc[b].x += v.x * dreg[t].x; acc[b].y += v.y * dreg[t].y;
            acc[b].z += v.z * dreg[t].z; acc[b].w += v.w * dreg[t].w;
        }
        // t=8 (shift 256): vE directly
        acc[b].x += vE.x * dreg[8].x; acc[b].y += vE.y * dreg[8].y;
        acc[b].z += vE.z * dreg[8].z; acc[b].w += vE.w * dreg[8].w;
        // t=9..15 (shifts 512..32768): direct loads
#pragma unroll
        for (int t = 9; t < 16; ++t) {
            const float4 v = vd[t - 9];
            acc[b].x += v.x * dreg[t].x; acc[b].y += v.y * dreg[t].y;
            acc[b].z += v.z * dreg[t].z; acc[b].w += v.w * dreg[t].w;
        }
    }

    // roll by 32768 == XOR top column bit; stores stay coalesced
#pragma unroll
    for (int b = 0; b < NB; ++b)
        *(float4*)(out + (size_t)(bg + b) * SLOTS + (j ^ 32768)) = acc[b];
}

extern "C" void kernel_launch(void* const* d_in, const int* in_sizes, int n_in,
                              void* d_out, int out_size, void* d_ws, size_t ws_size,
                              hipStream_t stream) {
    const float* x    = (const float*)d_in[0];   // (64, 65536) fp32
    const float* diag = (const float*)d_in[1];   // (16, 65536) fp32
    float* out        = (float*)d_out;           // (64, 65536) fp32
    // d_in[2] = stride (1), d_in[3] = reps (1) -- compile-time constants here.

    bsgs_kernel<<<dim3(1024), dim3(256), 0, stream>>>(x, diag, out);
}